// Round 13
// baseline (201.714 us; speedup 1.0000x reference)
//
#include <hip/hip_runtime.h>
#include <hip/hip_bf16.h>
#include <cstdint>
#include <cstddef>

#define NUM_REL    20000
#define NUM_EDGES  640000
#define DIM        128
#define NUM_HEAD   8
#define DIM_HID    16
#define NUM_BIN    10
#define CAP        128            // bucket capacity (P(overflow) ~ 4e-13)
#define PROJ_BLKS  471            // 157 M-tiles x 3 output matrices
#define SC_BLKS    2500           // ceil(640000 / 256)

using u16 = unsigned short;
using u32 = unsigned int;
typedef __attribute__((ext_vector_type(8))) short bf16x8;
typedef __attribute__((ext_vector_type(4))) float f32x4;

__device__ __forceinline__ float b2f(u16 u) { return __uint_as_float(((u32)u) << 16); }
__device__ __forceinline__ float lo2f(u32 u) { return __uint_as_float(u << 16); }
__device__ __forceinline__ float hi2f(u32 u) { return __uint_as_float(u & 0xffff0000u); }
__device__ __forceinline__ float lrelu(float x) { return fmaxf(x, 0.2f * x); }
__device__ __forceinline__ int clampi(int v, int hi) { return v < 0 ? 0 : (v > hi ? hi : v); }
__device__ __forceinline__ float ldf(const void* p, int f32m, int i)
{ return f32m ? ((const float*)p)[i] : b2f(((const u16*)p)[i]); }
__device__ __forceinline__ u16 f2b(float x)
{ u32 u = __float_as_uint(x); u += 0x7fffu + ((u >> 16) & 1u); return (u16)(u >> 16); }
__device__ __forceinline__ u32 pk2(float a, float b)
{ return (u32)f2b(a) | ((u32)f2b(b) << 16); }

// ---------------------------------------------------------------------------
// Per-block layout detection (proven R3 logic, block-local). Deterministic
// inputs -> all blocks agree. sF[0]=is64, sF[1]=f32m.
// ---------------------------------------------------------------------------
__device__ __forceinline__ void detect_flags(const int* __restrict__ trip,
                                             const u16* __restrict__ emb,
                                             int* sF, int tid)
{
    if (tid < 64) {
        bool odd_zero = (trip[2 * tid + 1] == 0) && (trip[2 * tid + 129] == 0);
        unsigned long long m1 = __ballot(odd_zero);
        int ex = (emb[2 * tid] >> 7) & 0xFF;
        bool inr = (ex >= 110) && (ex <= 136);
        unsigned long long m2 = __ballot(inr);
        if (tid == 0) {
            sF[0] = (~m1 == 0ull) ? 1 : 0;
            sF[1] = (__popcll(m2) >= 32) ? 0 : 1;   // few in-range => fp32
        }
    }
    __syncthreads();
}

// ---------------------------------------------------------------------------
// K1: fused [MFMA projections (blocks 0..470)] || [bucket scatter (471+)].
// nt=0: A=emb@Wa1^T (fp32); nt=1: B=emb@Wa2^T+b (bf16, SPLIT-HALF layout:
// row = [hd0..7 d0..7 | hd0..7 d8..15], 8 u16 per (hd,half) chunk -> the
// segment gather touches 2 lines per instruction instead of 4);
// nt=2: M=emb@Wg^T+b (bf16, natural). cnt zeroed by hipMemsetAsync.
// ---------------------------------------------------------------------------
__global__ __launch_bounds__(256) void k_projscatter(
    const void* __restrict__ emb, const int* __restrict__ trip,
    const void* __restrict__ w_attn, const void* __restrict__ w_aggr,
    const void* __restrict__ b_attn, const void* __restrict__ b_aggr,
    float* __restrict__ A, u16* __restrict__ Bb, u16* __restrict__ Mb,
    int* __restrict__ cnt, int* __restrict__ bucket)
{
    __shared__ u16 sA[128 * 128];    // 32 KB
    __shared__ u16 sW[128 * 128];    // 32 KB
    __shared__ float sBias[128];
    __shared__ int sF[2];

    const int tid = threadIdx.x;
    detect_flags(trip, (const u16*)emb, sF, tid);
    const int is64 = sF[0], f32m = sF[1];

    if (blockIdx.x >= PROJ_BLKS) {
        // ---------------- scatter ----------------
        int e = (blockIdx.x - PROJ_BLKS) * 256 + tid;
        if (e < NUM_EDGES) {
            int h, t, b;
            if (is64) { h = trip[6 * e]; t = trip[6 * e + 2]; b = trip[6 * e + 4]; }
            else      { h = trip[3 * e]; t = trip[3 * e + 1]; b = trip[3 * e + 2]; }
            h = clampi(h, NUM_REL - 1);
            t = clampi(t, NUM_REL - 1);
            b = clampi(b, NUM_BIN - 1);
            int pos = atomicAdd(&cnt[h], 1);
            if (pos < CAP) bucket[h * CAP + pos] = t | (b << 20);
        }
        return;
    }

    // ---------------- projection tile ----------------
    const int mt = blockIdx.x / 3, nt = blockIdx.x % 3;
    const int r0 = mt * 128;

    if (tid < 128)
        sBias[tid] = (nt == 0) ? 0.f : ldf((nt == 1) ? b_attn : b_aggr, f32m, tid);

    if (f32m) {
        const float* src = (const float*)emb;
        #pragma unroll
        for (int i = 0; i < 16; ++i) {
            int f = i * 256 + tid;
            int row = f >> 5, pos = f & 31;
            int g = r0 + row;
            float4 x = (g < NUM_REL) ? ((const float4*)(src + (size_t)g * DIM))[pos]
                                     : make_float4(0.f, 0.f, 0.f, 0.f);
            int chunk = (pos >> 1) ^ (row & 15);
            *(uint2*)&sA[row * 128 + chunk * 8 + (pos & 1) * 4] =
                make_uint2(pk2(x.x, x.y), pk2(x.z, x.w));
        }
    } else {
        const u16* src = (const u16*)emb;
        #pragma unroll
        for (int i = 0; i < 8; ++i) {
            int f = i * 256 + tid;
            int row = f >> 4, pos = f & 15;
            int g = r0 + row;
            uint4 x = (g < NUM_REL) ? ((const uint4*)(src + (size_t)g * DIM))[pos]
                                    : make_uint4(0, 0, 0, 0);
            int chunk = pos ^ (row & 15);
            *(uint4*)&sA[row * 128 + chunk * 8] = x;
        }
    }

    {
        const void* wsrc = (nt == 2) ? w_aggr : w_attn;
        const int stride = (nt == 2) ? 128 : 256;
        const int koff   = (nt == 1) ? 128 : 0;
        if (f32m) {
            const float* src = (const float*)wsrc;
            #pragma unroll
            for (int i = 0; i < 16; ++i) {
                int f = i * 256 + tid;
                int row = f >> 5, pos = f & 31;
                float4 x = ((const float4*)(src + (size_t)row * stride + koff))[pos];
                int chunk = (pos >> 1) ^ (row & 15);
                *(uint2*)&sW[row * 128 + chunk * 8 + (pos & 1) * 4] =
                    make_uint2(pk2(x.x, x.y), pk2(x.z, x.w));
            }
        } else {
            const u16* src = (const u16*)wsrc;
            #pragma unroll
            for (int i = 0; i < 8; ++i) {
                int f = i * 256 + tid;
                int row = f >> 4, pos = f & 15;
                uint4 x = ((const uint4*)(src + (size_t)row * stride + koff))[pos];
                int chunk = pos ^ (row & 15);
                *(uint4*)&sW[row * 128 + chunk * 8] = x;
            }
        }
    }
    __syncthreads();

    const int lane = tid & 63, wid = tid >> 6;
    const int wm = (wid >> 1) * 64, wn = (wid & 1) * 64;
    const int ln15 = lane & 15, q = lane >> 4;

    f32x4 acc[4][4] = {};
    #pragma unroll
    for (int kk = 0; kk < 4; ++kk) {
        const int cbase = kk * 4 + q;
        bf16x8 a[4], b[4];
        #pragma unroll
        for (int mi = 0; mi < 4; ++mi) {
            int m = wm + mi * 16 + ln15;
            int c = cbase ^ ln15;
            a[mi] = *(const bf16x8*)&sA[m * 128 + c * 8];
        }
        #pragma unroll
        for (int ni = 0; ni < 4; ++ni) {
            int n = wn + ni * 16 + ln15;
            int c = cbase ^ ln15;
            b[ni] = *(const bf16x8*)&sW[n * 128 + c * 8];
        }
        #pragma unroll
        for (int mi = 0; mi < 4; ++mi)
            #pragma unroll
            for (int ni = 0; ni < 4; ++ni)
                acc[mi][ni] = __builtin_amdgcn_mfma_f32_16x16x32_bf16(
                    a[mi], b[ni], acc[mi][ni], 0, 0, 0);
    }

    #pragma unroll
    for (int mi = 0; mi < 4; ++mi) {
        #pragma unroll
        for (int reg = 0; reg < 4; ++reg) {
            int g = r0 + wm + mi * 16 + q * 4 + reg;
            if (g < NUM_REL) {
                #pragma unroll
                for (int ni = 0; ni < 4; ++ni) {
                    int c = wn + ni * 16 + ln15;     // logical col = hd*16 + d
                    float v = acc[mi][ni][reg] + sBias[c];
                    if (nt == 0) {
                        A[(size_t)g * DIM + c] = v;
                    } else if (nt == 1) {
                        int hd = c >> 4, d = c & 15;
                        int pos = ((d >> 3) << 6) + hd * 8 + (d & 7);  // split-half
                        Bb[(size_t)g * DIM + pos] = f2b(v);
                    } else {
                        Mb[(size_t)g * DIM + c] = f2b(v);
                    }
                }
            }
        }
    }
}

// ---------------------------------------------------------------------------
// K5: R8/R11's proven segment loop (8-edge tiles, guarded loads, no manual
// prefetch — the compiler schedules these loads early on its own). B reads
// use the split-half layout: q0 = chunk hd (d0..7) in bytes [0,128),
// q1 = chunk 8+hd (d8..15) in bytes [128,256) -> 2 lines per instruction.
// ---------------------------------------------------------------------------
__global__ __launch_bounds__(256, 6) void k_segment(
    const float* __restrict__ A, const u16* __restrict__ Bb,
    const u16* __restrict__ Mb, const void* __restrict__ attn_bin,
    const void* __restrict__ attn_vec, const int* __restrict__ cnt,
    const int* __restrict__ bucket, const int* __restrict__ trip,
    const void* __restrict__ emb, void* __restrict__ out)
{
    __shared__ float sAr[4][DIM];
    __shared__ float sVec[DIM];
    __shared__ float sBin[NUM_BIN * NUM_HEAD];
    __shared__ int sF[2];

    const int tid  = threadIdx.x;
    detect_flags(trip, (const u16*)emb, sF, tid);
    const int f32m = sF[1];

    const int wid  = tid >> 6, lane = tid & 63;
    const int r = blockIdx.x * 4 + wid;
    int nE = cnt[r]; if (nE > CAP) nE = CAP;
    const int* __restrict__ bk = bucket + r * CAP;

    {
        const float2* ap = (const float2*)(A + (size_t)r * DIM);
        float2 a2 = ap[lane];
        sAr[wid][2 * lane] = a2.x; sAr[wid][2 * lane + 1] = a2.y;
    }
    if (tid < DIM) sVec[tid] = ldf(attn_vec, f32m, tid);
    else if (tid < DIM + NUM_BIN * NUM_HEAD)
        sBin[tid - DIM] = lrelu(ldf(attn_bin, f32m, tid - DIM));
    __syncthreads();

    if (nE == 0) {
        if (f32m) ((float2*)out)[(size_t)r * 64 + lane] = make_float2(0.f, 0.f);
        else      ((u32*)out)[(size_t)r * 64 + lane] = 0;
        return;
    }

    const int el = lane >> 3, hd = lane & 7;
    const int ah = lane >> 3;              // head owning this lane's out dims

    float av[16], vv[16];
    {
        const float4* pA = (const float4*)(&sAr[wid][hd * DIM_HID]);
        const float4* pV = (const float4*)(&sVec[hd * DIM_HID]);
        #pragma unroll
        for (int i = 0; i < 4; ++i) {
            float4 a4 = pA[i], v4 = pV[i];
            av[4*i+0]=a4.x; av[4*i+1]=a4.y; av[4*i+2]=a4.z; av[4*i+3]=a4.w;
            vv[4*i+0]=v4.x; vv[4*i+1]=v4.y; vv[4*i+2]=v4.z; vv[4*i+3]=v4.w;
        }
    }

    float l = 0.f, accx = 0.f, accy = 0.f;

    for (int base = 0; base < nE; base += 8) {
        int e = base + el;
        bool act = e < nE;
        int tb = 0;
        if (act) tb = bk[e];
        int t = tb & 0xFFFFF;
        float p = 0.f;
        if (act) {
            int b = (tb >> 20) & 0xF;
            const uint4* Bt = (const uint4*)(Bb + (size_t)t * DIM);
            uint4 q0 = Bt[hd];          // d0..7  (bytes [0,128): 2 lines/instr)
            uint4 q1 = Bt[8 + hd];      // d8..15 (bytes [128,256): 2 lines)
            float s = sBin[b * NUM_HEAD + hd];
            s += lrelu(av[0]  + lo2f(q0.x)) * vv[0];
            s += lrelu(av[1]  + hi2f(q0.x)) * vv[1];
            s += lrelu(av[2]  + lo2f(q0.y)) * vv[2];
            s += lrelu(av[3]  + hi2f(q0.y)) * vv[3];
            s += lrelu(av[4]  + lo2f(q0.z)) * vv[4];
            s += lrelu(av[5]  + hi2f(q0.z)) * vv[5];
            s += lrelu(av[6]  + lo2f(q0.w)) * vv[6];
            s += lrelu(av[7]  + hi2f(q0.w)) * vv[7];
            s += lrelu(av[8]  + lo2f(q1.x)) * vv[8];
            s += lrelu(av[9]  + hi2f(q1.x)) * vv[9];
            s += lrelu(av[10] + lo2f(q1.y)) * vv[10];
            s += lrelu(av[11] + hi2f(q1.y)) * vv[11];
            s += lrelu(av[12] + lo2f(q1.z)) * vv[12];
            s += lrelu(av[13] + hi2f(q1.z)) * vv[13];
            s += lrelu(av[14] + lo2f(q1.w)) * vv[14];
            s += lrelu(av[15] + hi2f(q1.w)) * vv[15];
            s = fminf(fmaxf(s, -60.f), 60.f);
            p = __expf(s);
        }
        l += p;

        int lim = nE - base; if (lim > 8) lim = 8;
        #pragma unroll
        for (int k = 0; k < 8; ++k) {
            if (k < lim) {
                float v = __shfl(p, k * 8 + ah);
                int tk  = __shfl(t, k * 8);
                u32 mm = *(const u32*)(Mb + (size_t)tk * DIM + 2 * lane);
                accx += v * lo2f(mm);
                accy += v * hi2f(mm);
            }
        }
    }

    float lt = l + __shfl_xor(l, 8);
    lt += __shfl_xor(lt, 16);
    lt += __shfl_xor(lt, 32);
    float lA = __shfl(lt, ah);
    float inv = 1.0f / (lA + 1e-16f);
    float o0 = accx * inv, o1 = accy * inv;
    if (f32m) {
        ((float2*)out)[(size_t)r * 64 + lane] = make_float2(o0, o1);
    } else {
        u32 pk = (u32)f2b(o0) | ((u32)f2b(o1) << 16);
        ((u32*)out)[(size_t)r * 64 + lane] = pk;
    }
}

// ---------------------------------------------------------------------------
extern "C" void kernel_launch(void* const* d_in, const int* in_sizes, int n_in,
                              void* d_out, int out_size, void* d_ws, size_t ws_size,
                              hipStream_t stream)
{
    (void)in_sizes; (void)n_in; (void)out_size; (void)ws_size;
    const void* emb      = d_in[0];
    const int*  trip     = (const int*)d_in[1];
    const void* w_attn   = d_in[2];
    const void* b_attn   = d_in[3];
    const void* attn_bin = d_in[4];
    const void* attn_vec = d_in[5];
    const void* w_aggr   = d_in[6];
    const void* b_aggr   = d_in[7];

    // workspace carve (~30.4 MB)
    char* p = (char*)d_ws;
    float* A      = (float*)p; p += (size_t)NUM_REL * DIM * 4;
    u16*   Bb     = (u16*)p;   p += (size_t)NUM_REL * DIM * 2;
    u16*   Mb     = (u16*)p;   p += (size_t)NUM_REL * DIM * 2;
    int*   bucket = (int*)p;   p += (size_t)NUM_REL * CAP * 4;
    int*   cnt    = (int*)p;   p += (size_t)NUM_REL * 4;

    hipMemsetAsync(cnt, 0, NUM_REL * sizeof(int), stream);
    k_projscatter<<<PROJ_BLKS + SC_BLKS, 256, 0, stream>>>(
        emb, trip, w_attn, w_aggr, b_attn, b_aggr, A, Bb, Mb, cnt, bucket);
    k_segment<<<NUM_REL / 4, 256, 0, stream>>>(A, Bb, Mb, attn_bin, attn_vec,
                                               cnt, bucket, trip, emb, d_out);
}

// Round 15
// 183.651 us; speedup vs baseline: 1.0984x; 1.0984x over previous
//
#include <hip/hip_runtime.h>
#include <hip/hip_bf16.h>
#include <cstdint>
#include <cstddef>

#define NUM_REL    20000
#define NUM_EDGES  640000
#define DIM        128
#define NUM_HEAD   8
#define DIM_HID    16
#define NUM_BIN    10
#define CAP        128            // bucket capacity (P(overflow) ~ 4e-13)
#define PROJ_BLKS  471            // 157 M-tiles x 3 output matrices
#define SC_BLKS    2500           // ceil(640000 / 256)

using u16 = unsigned short;
using u32 = unsigned int;
typedef __attribute__((ext_vector_type(8))) short bf16x8;
typedef __attribute__((ext_vector_type(4))) float f32x4;

__device__ __forceinline__ float b2f(u16 u) { return __uint_as_float(((u32)u) << 16); }
__device__ __forceinline__ float lo2f(u32 u) { return __uint_as_float(u << 16); }
__device__ __forceinline__ float hi2f(u32 u) { return __uint_as_float(u & 0xffff0000u); }
__device__ __forceinline__ float lrelu(float x) { return fmaxf(x, 0.2f * x); }
__device__ __forceinline__ int clampi(int v, int hi) { return v < 0 ? 0 : (v > hi ? hi : v); }
__device__ __forceinline__ float ldf(const void* p, int f32m, int i)
{ return f32m ? ((const float*)p)[i] : b2f(((const u16*)p)[i]); }
__device__ __forceinline__ u16 f2b(float x)
{ u32 u = __float_as_uint(x); u += 0x7fffu + ((u >> 16) & 1u); return (u16)(u >> 16); }
__device__ __forceinline__ u32 pk2(float a, float b)
{ return (u32)f2b(a) | ((u32)f2b(b) << 16); }

// ---------------------------------------------------------------------------
// Per-block layout detection (proven R3 logic, block-local). Deterministic
// inputs -> all blocks agree. sF[0]=is64, sF[1]=f32m.
// ---------------------------------------------------------------------------
__device__ __forceinline__ void detect_flags(const int* __restrict__ trip,
                                             const u16* __restrict__ emb,
                                             int* sF, int tid)
{
    if (tid < 64) {
        bool odd_zero = (trip[2 * tid + 1] == 0) && (trip[2 * tid + 129] == 0);
        unsigned long long m1 = __ballot(odd_zero);
        int ex = (emb[2 * tid] >> 7) & 0xFF;
        bool inr = (ex >= 110) && (ex <= 136);
        unsigned long long m2 = __ballot(inr);
        if (tid == 0) {
            sF[0] = (~m1 == 0ull) ? 1 : 0;
            sF[1] = (__popcll(m2) >= 32) ? 0 : 1;   // few in-range => fp32
        }
    }
    __syncthreads();
}

// ---------------------------------------------------------------------------
// K1: fused [MFMA projections (blocks 0..470)] || [bucket scatter (471+)].
// nt=0: A=emb@Wa1^T (fp32); nt=1: B=emb@Wa2^T+b (bf16); nt=2: M=emb@Wg^T+b.
// A-fragments are read DIRECTLY from global emb (zero intra-block reuse ->
// LDS staging was pure overhead); W tile (2x intra-block, 157x cross-block
// reuse) stays LDS-staged with the XOR-chunk swizzle. cnt zeroed by memset.
// ---------------------------------------------------------------------------
__global__ __launch_bounds__(256) void k_projscatter(
    const void* __restrict__ emb, const int* __restrict__ trip,
    const void* __restrict__ w_attn, const void* __restrict__ w_aggr,
    const void* __restrict__ b_attn, const void* __restrict__ b_aggr,
    float* __restrict__ A, u16* __restrict__ Bb, u16* __restrict__ Mb,
    int* __restrict__ cnt, int* __restrict__ bucket)
{
    __shared__ u16 sW[128 * 128];    // 32 KB
    __shared__ float sBias[128];
    __shared__ int sF[2];

    const int tid = threadIdx.x;
    detect_flags(trip, (const u16*)emb, sF, tid);
    const int is64 = sF[0], f32m = sF[1];

    if (blockIdx.x >= PROJ_BLKS) {
        // ---------------- scatter ----------------
        int e = (blockIdx.x - PROJ_BLKS) * 256 + tid;
        if (e < NUM_EDGES) {
            int h, t, b;
            if (is64) { h = trip[6 * e]; t = trip[6 * e + 2]; b = trip[6 * e + 4]; }
            else      { h = trip[3 * e]; t = trip[3 * e + 1]; b = trip[3 * e + 2]; }
            h = clampi(h, NUM_REL - 1);
            t = clampi(t, NUM_REL - 1);
            b = clampi(b, NUM_BIN - 1);
            int pos = atomicAdd(&cnt[h], 1);
            if (pos < CAP) bucket[h * CAP + pos] = t | (b << 20);
        }
        return;
    }

    // ---------------- projection tile ----------------
    const int mt = blockIdx.x / 3, nt = blockIdx.x % 3;
    const int r0 = mt * 128;

    if (tid < 128)
        sBias[tid] = (nt == 0) ? 0.f : ldf((nt == 1) ? b_attn : b_aggr, f32m, tid);

    // stage W tile into LDS (XOR-chunk swizzle; conflict-free b128 reads)
    {
        const void* wsrc = (nt == 2) ? w_aggr : w_attn;
        const int stride = (nt == 2) ? 128 : 256;
        const int koff   = (nt == 1) ? 128 : 0;
        if (f32m) {
            const float* src = (const float*)wsrc;
            #pragma unroll
            for (int i = 0; i < 16; ++i) {
                int f = i * 256 + tid;
                int row = f >> 5, pos = f & 31;
                float4 x = ((const float4*)(src + (size_t)row * stride + koff))[pos];
                int chunk = (pos >> 1) ^ (row & 15);
                *(uint2*)&sW[row * 128 + chunk * 8 + (pos & 1) * 4] =
                    make_uint2(pk2(x.x, x.y), pk2(x.z, x.w));
            }
        } else {
            const u16* src = (const u16*)wsrc;
            #pragma unroll
            for (int i = 0; i < 8; ++i) {
                int f = i * 256 + tid;
                int row = f >> 4, pos = f & 15;
                uint4 x = ((const uint4*)(src + (size_t)row * stride + koff))[pos];
                int chunk = pos ^ (row & 15);
                *(uint4*)&sW[row * 128 + chunk * 8] = x;
            }
        }
    }
    __syncthreads();

    const int lane = tid & 63, wid = tid >> 6;
    const int wm = (wid >> 1) * 64, wn = (wid & 1) * 64;
    const int ln15 = lane & 15, q = lane >> 4;

    // A-frag source rows (clamped; epilogue guards the stores)
    int arow[4];
    #pragma unroll
    for (int mi = 0; mi < 4; ++mi) {
        int g = r0 + wm + mi * 16 + ln15;
        arow[mi] = (g < NUM_REL) ? g : (NUM_REL - 1);
    }

    f32x4 acc[4][4] = {};
    #pragma unroll
    for (int kk = 0; kk < 4; ++kk) {
        const int cbase = kk * 4 + q;      // chunk index = k>>3
        const int kc = cbase * 8;          // element offset within row
        bf16x8 a[4], b[4];
        #pragma unroll
        for (int mi = 0; mi < 4; ++mi) {
            if (f32m) {
                const float* er = (const float*)emb + (size_t)arow[mi] * DIM + kc;
                float4 x0 = *(const float4*)er;
                float4 x1 = *(const float4*)(er + 4);
                union { bf16x8 v; u32 u[4]; } cv;
                cv.u[0] = pk2(x0.x, x0.y); cv.u[1] = pk2(x0.z, x0.w);
                cv.u[2] = pk2(x1.x, x1.y); cv.u[3] = pk2(x1.z, x1.w);
                a[mi] = cv.v;
            } else {
                a[mi] = *(const bf16x8*)((const u16*)emb + (size_t)arow[mi] * DIM + kc);
            }
        }
        #pragma unroll
        for (int ni = 0; ni < 4; ++ni) {
            int n = wn + ni * 16 + ln15;
            int c = cbase ^ ln15;
            b[ni] = *(const bf16x8*)&sW[n * 128 + c * 8];
        }
        #pragma unroll
        for (int mi = 0; mi < 4; ++mi)
            #pragma unroll
            for (int ni = 0; ni < 4; ++ni)
                acc[mi][ni] = __builtin_amdgcn_mfma_f32_16x16x32_bf16(
                    a[mi], b[ni], acc[mi][ni], 0, 0, 0);
    }

    #pragma unroll
    for (int mi = 0; mi < 4; ++mi) {
        #pragma unroll
        for (int reg = 0; reg < 4; ++reg) {
            int g = r0 + wm + mi * 16 + q * 4 + reg;
            if (g < NUM_REL) {
                #pragma unroll
                for (int ni = 0; ni < 4; ++ni) {
                    int c = wn + ni * 16 + ln15;
                    float v = acc[mi][ni][reg] + sBias[c];
                    size_t o = (size_t)g * DIM + c;
                    if (nt == 0)      A[o]  = v;
                    else if (nt == 1) Bb[o] = f2b(v);
                    else              Mb[o] = f2b(v);
                }
            }
        }
    }
}

// ---------------------------------------------------------------------------
// K5: R8/R11's proven segment loop (8-edge tiles, guarded loads, natural Bb
// layout, no manual prefetch). One WAVE per relation, 4 waves/block.
// ---------------------------------------------------------------------------
__global__ __launch_bounds__(256, 6) void k_segment(
    const float* __restrict__ A, const u16* __restrict__ Bb,
    const u16* __restrict__ Mb, const void* __restrict__ attn_bin,
    const void* __restrict__ attn_vec, const int* __restrict__ cnt,
    const int* __restrict__ bucket, const int* __restrict__ trip,
    const void* __restrict__ emb, void* __restrict__ out)
{
    __shared__ float sAr[4][DIM];
    __shared__ float sVec[DIM];
    __shared__ float sBin[NUM_BIN * NUM_HEAD];
    __shared__ int sF[2];

    const int tid  = threadIdx.x;
    detect_flags(trip, (const u16*)emb, sF, tid);
    const int f32m = sF[1];

    const int wid  = tid >> 6, lane = tid & 63;
    const int r = blockIdx.x * 4 + wid;
    int nE = cnt[r]; if (nE > CAP) nE = CAP;
    const int* __restrict__ bk = bucket + r * CAP;

    {
        const float2* ap = (const float2*)(A + (size_t)r * DIM);
        float2 a2 = ap[lane];
        sAr[wid][2 * lane] = a2.x; sAr[wid][2 * lane + 1] = a2.y;
    }
    if (tid < DIM) sVec[tid] = ldf(attn_vec, f32m, tid);
    else if (tid < DIM + NUM_BIN * NUM_HEAD)
        sBin[tid - DIM] = lrelu(ldf(attn_bin, f32m, tid - DIM));
    __syncthreads();

    if (nE == 0) {
        if (f32m) ((float2*)out)[(size_t)r * 64 + lane] = make_float2(0.f, 0.f);
        else      ((u32*)out)[(size_t)r * 64 + lane] = 0;
        return;
    }

    const int el = lane >> 3, hd = lane & 7;
    const int ah = lane >> 3;              // head owning this lane's out dims

    float av[16], vv[16];
    {
        const float4* pA = (const float4*)(&sAr[wid][hd * DIM_HID]);
        const float4* pV = (const float4*)(&sVec[hd * DIM_HID]);
        #pragma unroll
        for (int i = 0; i < 4; ++i) {
            float4 a4 = pA[i], v4 = pV[i];
            av[4*i+0]=a4.x; av[4*i+1]=a4.y; av[4*i+2]=a4.z; av[4*i+3]=a4.w;
            vv[4*i+0]=v4.x; vv[4*i+1]=v4.y; vv[4*i+2]=v4.z; vv[4*i+3]=v4.w;
        }
    }

    float l = 0.f, accx = 0.f, accy = 0.f;

    for (int base = 0; base < nE; base += 8) {
        int e = base + el;
        bool act = e < nE;
        int tb = 0;
        if (act) tb = bk[e];
        int t = tb & 0xFFFFF;
        float p = 0.f;
        if (act) {
            int b = (tb >> 20) & 0xF;
            const uint4* Bt = (const uint4*)(Bb + (size_t)t * DIM) + hd * 2;
            uint4 q0 = Bt[0], q1 = Bt[1];
            float s = sBin[b * NUM_HEAD + hd];
            s += lrelu(av[0]  + lo2f(q0.x)) * vv[0];
            s += lrelu(av[1]  + hi2f(q0.x)) * vv[1];
            s += lrelu(av[2]  + lo2f(q0.y)) * vv[2];
            s += lrelu(av[3]  + hi2f(q0.y)) * vv[3];
            s += lrelu(av[4]  + lo2f(q0.z)) * vv[4];
            s += lrelu(av[5]  + hi2f(q0.z)) * vv[5];
            s += lrelu(av[6]  + lo2f(q0.w)) * vv[6];
            s += lrelu(av[7]  + hi2f(q0.w)) * vv[7];
            s += lrelu(av[8]  + lo2f(q1.x)) * vv[8];
            s += lrelu(av[9]  + hi2f(q1.x)) * vv[9];
            s += lrelu(av[10] + lo2f(q1.y)) * vv[10];
            s += lrelu(av[11] + hi2f(q1.y)) * vv[11];
            s += lrelu(av[12] + lo2f(q1.z)) * vv[12];
            s += lrelu(av[13] + hi2f(q1.z)) * vv[13];
            s += lrelu(av[14] + lo2f(q1.w)) * vv[14];
            s += lrelu(av[15] + hi2f(q1.w)) * vv[15];
            s = fminf(fmaxf(s, -60.f), 60.f);
            p = __expf(s);
        }
        l += p;

        int lim = nE - base; if (lim > 8) lim = 8;
        #pragma unroll
        for (int k = 0; k < 8; ++k) {
            if (k < lim) {
                float v = __shfl(p, k * 8 + ah);
                int tk  = __shfl(t, k * 8);
                u32 mm = *(const u32*)(Mb + (size_t)tk * DIM + 2 * lane);
                accx += v * lo2f(mm);
                accy += v * hi2f(mm);
            }
        }
    }

    float lt = l + __shfl_xor(l, 8);
    lt += __shfl_xor(lt, 16);
    lt += __shfl_xor(lt, 32);
    float lA = __shfl(lt, ah);
    float inv = 1.0f / (lA + 1e-16f);
    float o0 = accx * inv, o1 = accy * inv;
    if (f32m) {
        ((float2*)out)[(size_t)r * 64 + lane] = make_float2(o0, o1);
    } else {
        u32 pk = (u32)f2b(o0) | ((u32)f2b(o1) << 16);
        ((u32*)out)[(size_t)r * 64 + lane] = pk;
    }
}

// ---------------------------------------------------------------------------
extern "C" void kernel_launch(void* const* d_in, const int* in_sizes, int n_in,
                              void* d_out, int out_size, void* d_ws, size_t ws_size,
                              hipStream_t stream)
{
    (void)in_sizes; (void)n_in; (void)out_size; (void)ws_size;
    const void* emb      = d_in[0];
    const int*  trip     = (const int*)d_in[1];
    const void* w_attn   = d_in[2];
    const void* b_attn   = d_in[3];
    const void* attn_bin = d_in[4];
    const void* attn_vec = d_in[5];
    const void* w_aggr   = d_in[6];
    const void* b_aggr   = d_in[7];

    // workspace carve (~30.4 MB)
    char* p = (char*)d_ws;
    float* A      = (float*)p; p += (size_t)NUM_REL * DIM * 4;
    u16*   Bb     = (u16*)p;   p += (size_t)NUM_REL * DIM * 2;
    u16*   Mb     = (u16*)p;   p += (size_t)NUM_REL * DIM * 2;
    int*   bucket = (int*)p;   p += (size_t)NUM_REL * CAP * 4;
    int*   cnt    = (int*)p;   p += (size_t)NUM_REL * 4;

    hipMemsetAsync(cnt, 0, NUM_REL * sizeof(int), stream);
    k_projscatter<<<PROJ_BLKS + SC_BLKS, 256, 0, stream>>>(
        emb, trip, w_attn, w_aggr, b_attn, b_aggr, A, Bb, Mb, cnt, bucket);
    k_segment<<<NUM_REL / 4, 256, 0, stream>>>(A, Bb, Mb, attn_bin, attn_vec,
                                               cnt, bucket, trip, emb, d_out);
}